// Round 2
// baseline (309.391 us; speedup 1.0000x reference)
//
#include <hip/hip_runtime.h>

// VQ-VAE VectorQuantizer forward for MI355X (gfx950).
// z_e: (64, 256, 32, 32) fp32; codebook: (512, 256) fp32.
// Outputs concatenated in d_out (float32):
//   [0, 16777216)        z_q_st  (== z_e + (z_q - z_e), fp32 elementwise)
//   [16777216]           commitment_loss
//   [16777217]           codebook_loss (same value)
//   [16777218, +65536)   indices (as float)
//
// Index semantics: bitwise emulation of numpy-fp32
//   d = sum(z**2,axis=1,keepdims=True) + sum(e**2,axis=1) - 2*matmul(z, e.T)
//   idx = argmin(d, axis=1)   (first occurrence on exact fp32 ties)
// with numpy pairwise summation for the norms and a sequential ascending-k
// fp32 FMA chain for the matmul (BLAS sgemm microkernel accumulation order).

namespace {
constexpr int K = 512;
constexpr int D = 256;
constexpr int HW = 1024;          // 32*32
constexpr int NROWS = 65536;      // 64*HW
constexpr int CHW = D * HW;       // 262144

constexpr int ZQ_SIZE = 64 * CHW; // 16777216
constexpr int LOSS0_OFF = ZQ_SIZE;
constexpr int LOSS1_OFF = ZQ_SIZE + 1;
constexpr int IDX_OFF = ZQ_SIZE + 2;

// workspace layout (float offsets)
constexpr int WS_ET = 0;                 // eT[256][512] transposed codebook
constexpr int WS_B = WS_ET + D * K;      // ||e_k||^2 (numpy pairwise), 512
constexpr int WS_IDX = WS_B + K;         // best index per row (int), 65536
constexpr int WS_PART = WS_IDX + NROWS;  // per-block loss partials, 1024
}  // namespace

// ---------------------------------------------------------------------------
// Kernel 1: transpose codebook into ws (eT[d][k]) and compute ||e_k||^2 with
// numpy pairwise-sum order: pw(x,256)=pw(x,128)+pw(x+128,128);
// pw(x,128): r[j]=x[j]; 15x r[j]+=x[8i+j]; ((r0+r1)+(r2+r3))+((r4+r5)+(r6+r7)).
__global__ void vq_prep(const float* __restrict__ cb, float* __restrict__ ws) {
    const int k = blockIdx.x;
    const int t = threadIdx.x;  // 0..255 == d
    ws[WS_ET + t * K + k] = cb[k * D + t];
    __shared__ float r16[16];
    if (t < 16) {
#pragma clang fp contract(off)
        const float* x = cb + k * D + (t >> 3) * 128;
        const int j = t & 7;
        float v = x[j];
        float r = v * v;
        for (int i = 1; i < 16; ++i) {
            float w = x[8 * i + j];
            r += w * w;
        }
        r16[t] = r;
    }
    __syncthreads();
    if (t == 0) {
#pragma clang fp contract(off)
        float lo = ((r16[0] + r16[1]) + (r16[2] + r16[3])) +
                   ((r16[4] + r16[5]) + (r16[6] + r16[7]));
        float hi = ((r16[8] + r16[9]) + (r16[10] + r16[11])) +
                   ((r16[12] + r16[13]) + (r16[14] + r16[15]));
        ws[WS_B + k] = lo + hi;
    }
}

// ---------------------------------------------------------------------------
// Kernel 2: fused score + argmin with numpy-fp32 tie semantics.
// Block: 256 threads; tile = 32 rows x all 512 codes.
// Per thread: 8 rows x 8 codes register tile; dot accumulated as a single
// sequential fp32 FMA chain over d = 0..255 ascending (bitwise sgemm order).
__global__ __launch_bounds__(256) void vq_argmin(
    const float* __restrict__ z_e, const float* __restrict__ eT,
    const float* __restrict__ Bv, int* __restrict__ wsidx) {
    __shared__ float lds_z[D][32];   // 32 KB, z[d][row]
    __shared__ float lds_e[8][K];    // 16 KB, e[dd][code]
    __shared__ float lds_B[K];       // 2 KB, ||e_k||^2
    __shared__ float lds_A[32];      // ||z_row||^2 (numpy pairwise)
    __shared__ float lds_r[32][16];  // pairwise partial accumulators

    const int t = threadIdx.x;
    const int row0 = blockIdx.x * 32;
    const int b = row0 >> 10;
    const int hw0 = row0 & 1023;

    // stage z tile (coalesced float4: 32 consecutive hw per channel)
    {
        const float4* zb4 = reinterpret_cast<const float4*>(z_e + b * CHW + hw0);
        float4* lz4 = reinterpret_cast<float4*>(&lds_z[0][0]);
        for (int i = t; i < 2048; i += 256) {
            int c = i >> 3, j4 = i & 7;
            lz4[c * 8 + j4] = zb4[c * 256 + j4];
        }
        lds_B[t] = Bv[t];
        lds_B[t + 256] = Bv[t + 256];
    }
    __syncthreads();

    // A = ||z_row||^2 in exact numpy pairwise order.
    // 512 chains (32 rows x 2 halves x 8 accumulators); 2 chains per thread.
    {
#pragma clang fp contract(off)
        const int row = t >> 3;
        const int half = (t >> 2) & 1;
        const int j0 = (t & 3) * 2;
        const int cbase = half * 128;
        float v0 = lds_z[cbase + j0][row];
        float v1 = lds_z[cbase + j0 + 1][row];
        float r0 = v0 * v0;
        float r1 = v1 * v1;
        for (int i = 1; i < 16; ++i) {
            float w0 = lds_z[cbase + 8 * i + j0][row];
            float w1 = lds_z[cbase + 8 * i + j0 + 1][row];
            r0 += w0 * w0;
            r1 += w1 * w1;
        }
        lds_r[row][half * 8 + j0] = r0;
        lds_r[row][half * 8 + j0 + 1] = r1;
    }
    __syncthreads();
    if (t < 32) {
#pragma clang fp contract(off)
        const float* r = lds_r[t];
        float lo = ((r[0] + r[1]) + (r[2] + r[3])) + ((r[4] + r[5]) + (r[6] + r[7]));
        float hi = ((r[8] + r[9]) + (r[10] + r[11])) + ((r[12] + r[13]) + (r[14] + r[15]));
        lds_A[t] = lo + hi;
    }

    float acc[8][8];
#pragma unroll
    for (int i = 0; i < 8; ++i)
#pragma unroll
        for (int j = 0; j < 8; ++j) acc[i][j] = 0.f;

    const int rg = t >> 6;   // row group 0..3  (== wave id)
    const int cg = t & 63;   // code group 0..63 (== lane id)

    const float4* eT4 = reinterpret_cast<const float4*>(eT);
    float4* le4 = reinterpret_cast<float4*>(&lds_e[0][0]);

    for (int d0 = 0; d0 < D; d0 += 8) {
        __syncthreads();
        for (int i = t; i < 1024; i += 256) {
            int dd = i >> 7, k4 = i & 127;
            le4[dd * 128 + k4] = eT4[(d0 + dd) * 128 + k4];
        }
        __syncthreads();
#pragma unroll
        for (int dd = 0; dd < 8; ++dd) {
            float4 za = *reinterpret_cast<const float4*>(&lds_z[d0 + dd][4 * rg]);
            float4 zb = *reinterpret_cast<const float4*>(&lds_z[d0 + dd][16 + 4 * rg]);
            float4 ea = *reinterpret_cast<const float4*>(&lds_e[dd][4 * cg]);
            float4 eb = *reinterpret_cast<const float4*>(&lds_e[dd][256 + 4 * cg]);
            float zr[8] = {za.x, za.y, za.z, za.w, zb.x, zb.y, zb.z, zb.w};
            float ec[8] = {ea.x, ea.y, ea.z, ea.w, eb.x, eb.y, eb.z, eb.w};
#pragma unroll
            for (int ri = 0; ri < 8; ++ri)
#pragma unroll
                for (int ci = 0; ci < 8; ++ci)
                    acc[ri][ci] = fmaf(zr[ri], ec[ci], acc[ri][ci]);
        }
    }

    // d = fl(fl(A + B) - 2*M); per-thread min over its 8 codes per row
    // (codes visited ascending -> strict < keeps first occurrence).
    float best[8];
    int bestk[8];
    {
#pragma clang fp contract(off)
        const int rbase = rg * 4;
#pragma unroll
        for (int ri = 0; ri < 8; ++ri) {
            const int rlocal = (ri < 4) ? (rbase + ri) : (16 + rbase + ri - 4);
            const float aval = lds_A[rlocal];
            best[ri] = 1e38f;
            bestk[ri] = 0;
#pragma unroll
            for (int ci = 0; ci < 8; ++ci) {
                const int code = (ci < 4) ? (4 * cg + ci) : (256 + 4 * cg + (ci - 4));
                float t1 = aval + lds_B[code];
                float d = t1 - 2.0f * acc[ri][ci];
                if (d < best[ri]) {
                    best[ri] = d;
                    bestk[ri] = code;
                }
            }
        }
    }

    // wave-wide (min d, then min k) butterfly reduce; lanes converge.
#pragma unroll
    for (int ri = 0; ri < 8; ++ri) {
#pragma unroll
        for (int m = 1; m < 64; m <<= 1) {
            float ov = __shfl_xor(best[ri], m);
            int ok = __shfl_xor(bestk[ri], m);
            if (ov < best[ri] || (ov == best[ri] && ok < bestk[ri])) {
                best[ri] = ov;
                bestk[ri] = ok;
            }
        }
    }

    if (cg == 0) {
        const int rbase = rg * 4;
#pragma unroll
        for (int ri = 0; ri < 8; ++ri) {
            const int rlocal = (ri < 4) ? (rbase + ri) : (16 + rbase + ri - 4);
            wsidx[row0 + rlocal] = bestk[ri];
        }
    }
}

// ---------------------------------------------------------------------------
// Kernel 3: gather z_q, write z_q_st + indices, per-block squared-diff sums.
// Block: 256 threads, 64 rows.
__global__ __launch_bounds__(256) void vq_gather(
    const float* __restrict__ z_e, const float* __restrict__ eT,
    const int* __restrict__ wsidx, float* __restrict__ part,
    float* __restrict__ out) {
    __shared__ int kidx[64];
    __shared__ float wpart[4];
    const int t = threadIdx.x;
    const int row0 = blockIdx.x * 64;
    const int b = row0 >> 10;
    const int hw0 = row0 & 1023;

    if (t < 64) {
        int kk = wsidx[row0 + t];
        kidx[t] = kk;
        out[IDX_OFF + row0 + t] = (float)kk;
    }
    __syncthreads();

    const int j = t & 63;
    const int cc = t >> 6;
    const int kme = kidx[j];
    const float* zb = z_e + b * CHW + hw0;
    float* ob = out + b * CHW + hw0;

    float accum = 0.f;
    for (int c = cc; c < D; c += 4) {
        float z = zb[c * HW + j];
        float e = eT[c * K + kme];
        ob[c * HW + j] = z + (e - z);  // straight-through value, fp32 like ref
        float df = z - e;
        accum = fmaf(df, df, accum);
    }
#pragma unroll
    for (int m = 1; m < 64; m <<= 1) accum += __shfl_xor(accum, m);
    if ((t & 63) == 0) wpart[t >> 6] = accum;
    __syncthreads();
    if (t == 0) part[blockIdx.x] = wpart[0] + wpart[1] + wpart[2] + wpart[3];
}

// ---------------------------------------------------------------------------
// Kernel 4: final loss reduction (1024 partials, fp64, deterministic).
__global__ void vq_finish(const float* __restrict__ part, float* __restrict__ out) {
    const int t = threadIdx.x;  // 256 threads
    double s = (double)part[t] + (double)part[t + 256] +
               (double)part[t + 512] + (double)part[t + 768];
#pragma unroll
    for (int m = 1; m < 64; m <<= 1) s += __shfl_xor(s, m);
    __shared__ double wsum[4];
    if ((t & 63) == 0) wsum[t >> 6] = s;
    __syncthreads();
    if (t == 0) {
        double mean = (wsum[0] + wsum[1] + wsum[2] + wsum[3]) / (double)ZQ_SIZE;
        out[LOSS0_OFF] = (float)mean;
        out[LOSS1_OFF] = (float)mean;
    }
}

// ---------------------------------------------------------------------------
extern "C" void kernel_launch(void* const* d_in, const int* in_sizes, int n_in,
                              void* d_out, int out_size, void* d_ws, size_t ws_size,
                              hipStream_t stream) {
    const float* z_e = (const float*)d_in[0];
    const float* cb = (const float*)d_in[1];
    float* out = (float*)d_out;
    float* ws = (float*)d_ws;

    float* eT = ws + WS_ET;
    float* Bv = ws + WS_B;
    int* wsidx = (int*)(ws + WS_IDX);
    float* part = ws + WS_PART;

    vq_prep<<<K, D, 0, stream>>>(cb, ws);
    vq_argmin<<<NROWS / 32, 256, 0, stream>>>(z_e, eT, Bv, wsidx);
    vq_gather<<<NROWS / 64, 256, 0, stream>>>(z_e, eT, wsidx, part, out);
    vq_finish<<<1, 256, 0, stream>>>(part, out);
}

// Round 3
// 269.890 us; speedup vs baseline: 1.1464x; 1.1464x over previous
//
#include <hip/hip_runtime.h>

// VQ-VAE VectorQuantizer forward for MI355X (gfx950).
// z_e: (64, 256, 32, 32) fp32; codebook: (512, 256) fp32.
// Outputs concatenated in d_out (float32):
//   [0, 16777216)        z_q_st  (== z_e + (z_q - z_e), fp32 elementwise)
//   [16777216]           commitment_loss
//   [16777217]           codebook_loss (same value)
//   [16777218, +65536)   indices (as float)
//
// Index semantics: bitwise emulation of numpy-fp32
//   d = sum(z**2,axis=1,keepdims=True) + sum(e**2,axis=1) - 2*matmul(z, e.T)
//   idx = argmin(d, axis=1)   (first occurrence on exact fp32 ties)
// with numpy pairwise summation for the norms and a sequential ascending-k
// fp32 FMA chain for the matmul (BLAS sgemm microkernel accumulation order).

namespace {
constexpr int K = 512;
constexpr int D = 256;
constexpr int HW = 1024;          // 32*32
constexpr int NROWS = 65536;      // 64*HW
constexpr int CHW = D * HW;       // 262144

constexpr int ZQ_SIZE = 64 * CHW; // 16777216
constexpr int LOSS0_OFF = ZQ_SIZE;
constexpr int LOSS1_OFF = ZQ_SIZE + 1;
constexpr int IDX_OFF = ZQ_SIZE + 2;

// workspace layout (float offsets)
constexpr int WS_ET = 0;                 // eT[256][512] transposed codebook
constexpr int WS_B = WS_ET + D * K;      // ||e_k||^2 (numpy pairwise), 512
constexpr int WS_IDX = WS_B + K;         // best index per row (int), 65536
constexpr int WS_PART = WS_IDX + NROWS;  // per-block loss partials, 1024
}  // namespace

// ---------------------------------------------------------------------------
// Kernel 1: transpose codebook into ws (eT[d][k]) and compute ||e_k||^2 with
// numpy pairwise-sum order.
__global__ void vq_prep(const float* __restrict__ cb, float* __restrict__ ws) {
    const int k = blockIdx.x;
    const int t = threadIdx.x;  // 0..255 == d
    ws[WS_ET + t * K + k] = cb[k * D + t];
    __shared__ float r16[16];
    if (t < 16) {
#pragma clang fp contract(off)
        const float* x = cb + k * D + (t >> 3) * 128;
        const int j = t & 7;
        float v = x[j];
        float r = v * v;
        for (int i = 1; i < 16; ++i) {
            float w = x[8 * i + j];
            r += w * w;
        }
        r16[t] = r;
    }
    __syncthreads();
    if (t == 0) {
#pragma clang fp contract(off)
        float lo = ((r16[0] + r16[1]) + (r16[2] + r16[3])) +
                   ((r16[4] + r16[5]) + (r16[6] + r16[7]));
        float hi = ((r16[8] + r16[9]) + (r16[10] + r16[11])) +
                   ((r16[12] + r16[13]) + (r16[14] + r16[15]));
        ws[WS_B + k] = lo + hi;
    }
}

// ---------------------------------------------------------------------------
// Kernel 2: fused score + argmin with numpy-fp32 tie semantics.
// Block: 256 threads; tile = 32 rows x all 512 codes.
// e is read directly from L2 (eT is 512 KB, L2-resident) with a 1-deep
// register prefetch -> NO barriers in the main loop. z is LDS-broadcast.
// Per thread: 8 rows x 8 codes; dot accumulated as a single sequential fp32
// FMA chain over d = 0..255 ascending (bitwise sgemm order).
__global__ __launch_bounds__(256, 4) void vq_argmin(
    const float* __restrict__ z_e, const float* __restrict__ eT,
    const float* __restrict__ Bv, int* __restrict__ wsidx) {
    __shared__ float lds_z[D][32];   // 32 KB, z[d][row]
    __shared__ float lds_B[K];       // 2 KB, ||e_k||^2
    __shared__ float lds_A[32];      // ||z_row||^2 (numpy pairwise)
    __shared__ float lds_r[32][16];  // pairwise partial accumulators

    const int t = threadIdx.x;
    const int row0 = blockIdx.x * 32;
    const int b = row0 >> 10;
    const int hw0 = row0 & 1023;

    // stage z tile (coalesced float4: 32 consecutive hw per channel)
    {
        const float4* zb4 = reinterpret_cast<const float4*>(z_e + b * CHW + hw0);
        float4* lz4 = reinterpret_cast<float4*>(&lds_z[0][0]);
        for (int i = t; i < 2048; i += 256) {
            int c = i >> 3, j4 = i & 7;
            lz4[c * 8 + j4] = zb4[c * 256 + j4];
        }
        lds_B[t] = Bv[t];
        lds_B[t + 256] = Bv[t + 256];
    }
    __syncthreads();

    // A = ||z_row||^2 in exact numpy pairwise order.
    // 512 chains (32 rows x 2 halves x 8 accumulators); 2 chains per thread.
    {
#pragma clang fp contract(off)
        const int row = t >> 3;
        const int half = (t >> 2) & 1;
        const int j0 = (t & 3) * 2;
        const int cbase = half * 128;
        float v0 = lds_z[cbase + j0][row];
        float v1 = lds_z[cbase + j0 + 1][row];
        float r0 = v0 * v0;
        float r1 = v1 * v1;
        for (int i = 1; i < 16; ++i) {
            float w0 = lds_z[cbase + 8 * i + j0][row];
            float w1 = lds_z[cbase + 8 * i + j0 + 1][row];
            r0 += w0 * w0;
            r1 += w1 * w1;
        }
        lds_r[row][half * 8 + j0] = r0;
        lds_r[row][half * 8 + j0 + 1] = r1;
    }
    __syncthreads();
    if (t < 32) {
#pragma clang fp contract(off)
        const float* r = lds_r[t];
        float lo = ((r[0] + r[1]) + (r[2] + r[3])) + ((r[4] + r[5]) + (r[6] + r[7]));
        float hi = ((r[8] + r[9]) + (r[10] + r[11])) + ((r[12] + r[13]) + (r[14] + r[15]));
        lds_A[t] = lo + hi;
    }
    __syncthreads();

    float acc[8][8];
#pragma unroll
    for (int i = 0; i < 8; ++i)
#pragma unroll
        for (int j = 0; j < 8; ++j) acc[i][j] = 0.f;

    const int rg = t >> 6;   // row group 0..3  (== wave id)
    const int cg = t & 63;   // code group 0..63 (== lane id)

    // e addresses: codes {4cg..4cg+3} and {256+4cg..256+4cg+3}; row stride
    // 512 floats = 128 float4. Last-iteration prefetch reads one row past
    // eT — that lands in ws[WS_B..], in-bounds of d_ws, value unused.
    const float4* pe_d = reinterpret_cast<const float4*>(eT) + cg;
    float4 ea = pe_d[0];
    float4 eb = pe_d[64];

#pragma unroll 4
    for (int d = 0; d < 256; ++d) {
        pe_d += 128;
        const float4 ean = pe_d[0];
        const float4 ebn = pe_d[64];
        const float4 za = *reinterpret_cast<const float4*>(&lds_z[d][4 * rg]);
        const float4 zb = *reinterpret_cast<const float4*>(&lds_z[d][16 + 4 * rg]);
        const float zr[8] = {za.x, za.y, za.z, za.w, zb.x, zb.y, zb.z, zb.w};
        const float ec[8] = {ea.x, ea.y, ea.z, ea.w, eb.x, eb.y, eb.z, eb.w};
#pragma unroll
        for (int ri = 0; ri < 8; ++ri)
#pragma unroll
            for (int ci = 0; ci < 8; ++ci)
                acc[ri][ci] = fmaf(zr[ri], ec[ci], acc[ri][ci]);
        ea = ean;
        eb = ebn;
    }

    // d = fl(fl(A + B) - 2*M); per-thread min over its 8 codes per row
    // (codes visited ascending -> strict < keeps first occurrence).
    float best[8];
    int bestk[8];
    {
#pragma clang fp contract(off)
        const int rbase = rg * 4;
#pragma unroll
        for (int ri = 0; ri < 8; ++ri) {
            const int rlocal = (ri < 4) ? (rbase + ri) : (16 + rbase + ri - 4);
            const float aval = lds_A[rlocal];
            best[ri] = 1e38f;
            bestk[ri] = 0;
#pragma unroll
            for (int ci = 0; ci < 8; ++ci) {
                const int code = (ci < 4) ? (4 * cg + ci) : (256 + 4 * cg + (ci - 4));
                float t1 = aval + lds_B[code];
                float d = t1 - 2.0f * acc[ri][ci];
                if (d < best[ri]) {
                    best[ri] = d;
                    bestk[ri] = code;
                }
            }
        }
    }

    // wave-wide (min d, then min k) butterfly reduce; lanes converge.
#pragma unroll
    for (int ri = 0; ri < 8; ++ri) {
#pragma unroll
        for (int m = 1; m < 64; m <<= 1) {
            float ov = __shfl_xor(best[ri], m);
            int ok = __shfl_xor(bestk[ri], m);
            if (ov < best[ri] || (ov == best[ri] && ok < bestk[ri])) {
                best[ri] = ov;
                bestk[ri] = ok;
            }
        }
    }

    if (cg == 0) {
        const int rbase = rg * 4;
#pragma unroll
        for (int ri = 0; ri < 8; ++ri) {
            const int rlocal = (ri < 4) ? (rbase + ri) : (16 + rbase + ri - 4);
            wsidx[row0 + rlocal] = bestk[ri];
        }
    }
}

// ---------------------------------------------------------------------------
// Kernel 3: gather z_q, write z_q_st + indices, per-block squared-diff sums.
// Block: 256 threads, 64 rows.
__global__ __launch_bounds__(256) void vq_gather(
    const float* __restrict__ z_e, const float* __restrict__ eT,
    const int* __restrict__ wsidx, float* __restrict__ part,
    float* __restrict__ out) {
    __shared__ int kidx[64];
    __shared__ float wpart[4];
    const int t = threadIdx.x;
    const int row0 = blockIdx.x * 64;
    const int b = row0 >> 10;
    const int hw0 = row0 & 1023;

    if (t < 64) {
        int kk = wsidx[row0 + t];
        kidx[t] = kk;
        out[IDX_OFF + row0 + t] = (float)kk;
    }
    __syncthreads();

    const int j = t & 63;
    const int cc = t >> 6;
    const int kme = kidx[j];
    const float* zb = z_e + b * CHW + hw0;
    float* ob = out + b * CHW + hw0;

    float accum = 0.f;
    for (int c = cc; c < D; c += 4) {
        float z = zb[c * HW + j];
        float e = eT[c * K + kme];
        ob[c * HW + j] = z + (e - z);  // straight-through value, fp32 like ref
        float df = z - e;
        accum = fmaf(df, df, accum);
    }
#pragma unroll
    for (int m = 1; m < 64; m <<= 1) accum += __shfl_xor(accum, m);
    if ((t & 63) == 0) wpart[t >> 6] = accum;
    __syncthreads();
    if (t == 0) part[blockIdx.x] = wpart[0] + wpart[1] + wpart[2] + wpart[3];
}

// ---------------------------------------------------------------------------
// Kernel 4: final loss reduction (1024 partials, fp64, deterministic).
__global__ void vq_finish(const float* __restrict__ part, float* __restrict__ out) {
    const int t = threadIdx.x;  // 256 threads
    double s = (double)part[t] + (double)part[t + 256] +
               (double)part[t + 512] + (double)part[t + 768];
#pragma unroll
    for (int m = 1; m < 64; m <<= 1) s += __shfl_xor(s, m);
    __shared__ double wsum[4];
    if ((t & 63) == 0) wsum[t >> 6] = s;
    __syncthreads();
    if (t == 0) {
        double mean = (wsum[0] + wsum[1] + wsum[2] + wsum[3]) / (double)ZQ_SIZE;
        out[LOSS0_OFF] = (float)mean;
        out[LOSS1_OFF] = (float)mean;
    }
}

// ---------------------------------------------------------------------------
extern "C" void kernel_launch(void* const* d_in, const int* in_sizes, int n_in,
                              void* d_out, int out_size, void* d_ws, size_t ws_size,
                              hipStream_t stream) {
    const float* z_e = (const float*)d_in[0];
    const float* cb = (const float*)d_in[1];
    float* out = (float*)d_out;
    float* ws = (float*)d_ws;

    float* eT = ws + WS_ET;
    float* Bv = ws + WS_B;
    int* wsidx = (int*)(ws + WS_IDX);
    float* part = ws + WS_PART;

    vq_prep<<<K, D, 0, stream>>>(cb, ws);
    vq_argmin<<<NROWS / 32, 256, 0, stream>>>(z_e, eT, Bv, wsidx);
    vq_gather<<<NROWS / 64, 256, 0, stream>>>(z_e, eT, wsidx, part, out);
    vq_finish<<<1, 256, 0, stream>>>(part, out);
}

// Round 4
// 131.741 us; speedup vs baseline: 2.3485x; 2.0486x over previous
//
#include <hip/hip_runtime.h>

// VQ-VAE VectorQuantizer forward for MI355X (gfx950) — MFMA-filtered argmin.
// z_e: (64, 256, 32, 32) fp32; codebook: (512, 256) fp32.
// Outputs concatenated in d_out (float32):
//   [0, 16777216)        z_q_st  (== z_e + (z_q - z_e), fp32 elementwise)
//   [16777216]           commitment_loss
//   [16777217]           codebook_loss (same value)
//   [16777218, +65536)   indices (as float)
//
// Index semantics: bitwise emulation of numpy-fp32
//   d = sum(z**2,axis=1,keepdims=True) + sum(e**2,axis=1) - 2*matmul(z, e.T)
//   idx = argmin(d, axis=1)   (first occurrence on exact fp32 ties)
// Strategy: bf16-split MFMA computes approximate scores (error << 2.5e-3);
// per-row candidates within EPS of the approx min are re-scored with the
// bitwise-exact sequential fp32 FMA chain (ascending d) and reduced with
// (d asc, tie -> lower k) — exactly numpy first-occurrence argmin.

typedef __attribute__((ext_vector_type(8))) short short8v;
typedef __attribute__((ext_vector_type(4))) float float4v;
typedef unsigned short ushort_t;

namespace {
constexpr int K = 512;
constexpr int D = 256;
constexpr int HW = 1024;          // 32*32
constexpr int NROWS = 65536;      // 64*HW
constexpr int CHW = D * HW;       // 262144

constexpr int ZQ_SIZE = 64 * CHW; // 16777216
constexpr int LOSS0_OFF = ZQ_SIZE;
constexpr int LOSS1_OFF = ZQ_SIZE + 1;
constexpr int IDX_OFF = ZQ_SIZE + 2;

// workspace layout (float offsets)
constexpr int WS_EH_FLOATS = (K * D) / 2;  // eH bf16[512][256] = 65536 floats
constexpr int WS_B = WS_EH_FLOATS;         // ||e_k||^2 (numpy pairwise), 512
constexpr int WS_PART = WS_B + K;          // per-block loss partials, 2048
constexpr int NBLK = NROWS / 32;           // 2048 blocks of 32 rows

constexpr float EPS_CAND = 2.5e-3f;        // candidate window (>> split error)
}  // namespace

__device__ __forceinline__ ushort_t bf16_rne(float f) {
    unsigned u = __float_as_uint(f);
    u += 0x7fffu + ((u >> 16) & 1u);   // round-to-nearest-even (no NaN in data)
    return (ushort_t)(u >> 16);
}
__device__ __forceinline__ float bf16_to_f(ushort_t h) {
    return __uint_as_float((unsigned)h << 16);
}

// ---------------------------------------------------------------------------
// Kernel 1: eH[k][d] = bf16(cb[k][d]); B[k] = ||e_k||^2 in numpy pairwise
// order: pw(x,256)=pw(x,128)+pw(x+128,128); pw(x,128): 8 accums x 16 strided
// adds, then ((r0+r1)+(r2+r3))+((r4+r5)+(r6+r7)).
__global__ void vq_prep(const float* __restrict__ cb, float* __restrict__ ws) {
    const int k = blockIdx.x;
    const int t = threadIdx.x;  // 0..255 == d
    ushort_t* eh = (ushort_t*)ws;
    eh[(size_t)k * D + t] = bf16_rne(cb[k * D + t]);
    __shared__ float r16[16];
    if (t < 16) {
#pragma clang fp contract(off)
        const float* x = cb + k * D + (t >> 3) * 128;
        const int j = t & 7;
        float v = x[j];
        float r = v * v;
        for (int i = 1; i < 16; ++i) {
            float w = x[8 * i + j];
            r += w * w;
        }
        r16[t] = r;
    }
    __syncthreads();
    if (t == 0) {
#pragma clang fp contract(off)
        float lo = ((r16[0] + r16[1]) + (r16[2] + r16[3])) +
                   ((r16[4] + r16[5]) + (r16[6] + r16[7]));
        float hi = ((r16[8] + r16[9]) + (r16[10] + r16[11])) +
                   ((r16[12] + r16[13]) + (r16[14] + r16[15]));
        ws[WS_B + k] = lo + hi;
    }
}

// ---------------------------------------------------------------------------
// Kernel 2 (mega): per 32-row block:
//   stage z fp32 -> LDS; exact pairwise A; bf16 hi/lo of z;
//   MFMA approx scores (4 waves x 128 codes x 32 rows);
//   per-row approx min + candidate collection (<= min+EPS);
//   exact fp32-chain re-score of candidates (rows with >=2 only);
//   gather/straight-through write + loss partial. One z read total.
__global__ __launch_bounds__(256, 2) void vq_mega(
    const float* __restrict__ z_e, const float* __restrict__ cb,
    const ushort_t* __restrict__ eh, const float* __restrict__ Bv,
    float* __restrict__ part, float* __restrict__ out) {
    __shared__ float zf[D][32];                       // 32 KB, z[d][row] fp32
    __shared__ __align__(16) ushort_t zh[32][264];    // bf16 hi, padded rows
    __shared__ __align__(16) ushort_t zl[32][264];    // bf16 lo
    __shared__ float lds_B[K];                        // ||e_k||^2
    __shared__ float lds_scratch[32][16];             // pairwise accums / cands
    __shared__ float lds_A[32];
    __shared__ float wmin[4][32];
    __shared__ float rmin[32];
    __shared__ int cnt[32];
    __shared__ float wpart[4];

    const int t = threadIdx.x;
    const int row0 = blockIdx.x * 32;
    const int b = row0 >> 10;
    const int hw0 = row0 & 1023;

    // ---- stage z tile (coalesced float4) + B
    {
        const float4* zb4 = reinterpret_cast<const float4*>(z_e + (size_t)b * CHW + hw0);
        float4* lz4 = reinterpret_cast<float4*>(&zf[0][0]);
        for (int i = t; i < 2048; i += 256) {
            int c = i >> 3, j4 = i & 7;
            lz4[c * 8 + j4] = zb4[c * 256 + j4];
        }
        lds_B[t] = Bv[t];
        lds_B[t + 256] = Bv[t + 256];
    }
    __syncthreads();

    // ---- A = ||z_row||^2 in exact numpy pairwise order (2 chains/thread)
    {
#pragma clang fp contract(off)
        const int row = t >> 3;
        const int half = (t >> 2) & 1;
        const int j0 = (t & 3) * 2;
        const int cbase = half * 128;
        float v0 = zf[cbase + j0][row];
        float v1 = zf[cbase + j0 + 1][row];
        float r0 = v0 * v0;
        float r1 = v1 * v1;
        for (int i = 1; i < 16; ++i) {
            float w0 = zf[cbase + 8 * i + j0][row];
            float w1 = zf[cbase + 8 * i + j0 + 1][row];
            r0 += w0 * w0;
            r1 += w1 * w1;
        }
        lds_scratch[row][half * 8 + j0] = r0;
        lds_scratch[row][half * 8 + j0 + 1] = r1;
    }
    // ---- bf16 hi/lo conversion of z (same barrier window; disjoint LDS)
    {
        const int row = t & 31;
        const int dc = t >> 5;  // 0..7, 32 d each
#pragma unroll
        for (int i = 0; i < 8; ++i) {
            const int d4 = dc * 32 + i * 4;
            ushort_t h[4], l[4];
#pragma unroll
            for (int q = 0; q < 4; ++q) {
                float f = zf[d4 + q][row];
                h[q] = bf16_rne(f);
                l[q] = bf16_rne(f - bf16_to_f(h[q]));
            }
            uint2 ph, pl;
            ph.x = (unsigned)h[0] | ((unsigned)h[1] << 16);
            ph.y = (unsigned)h[2] | ((unsigned)h[3] << 16);
            pl.x = (unsigned)l[0] | ((unsigned)l[1] << 16);
            pl.y = (unsigned)l[2] | ((unsigned)l[3] << 16);
            *reinterpret_cast<uint2*>(&zh[row][d4]) = ph;
            *reinterpret_cast<uint2*>(&zl[row][d4]) = pl;
        }
    }
    __syncthreads();
    if (t < 32) {
#pragma clang fp contract(off)
        const float* r = lds_scratch[t];
        float lo = ((r[0] + r[1]) + (r[2] + r[3])) + ((r[4] + r[5]) + (r[6] + r[7]));
        float hi = ((r[8] + r[9]) + (r[10] + r[11])) + ((r[12] + r[13]) + (r[14] + r[15]));
        lds_A[t] = lo + hi;
    }
    __syncthreads();

    // ---- MFMA main loop: wave w owns codes [w*128, w*128+128), all 32 rows.
    // Orientation: A = E (codes = M), B = Z (rows = N).
    // C frag (m89-verified): col = lane&15 = z-row; row = 4*(lane>>4)+reg = code.
    const int lane = t & 63;
    const int w = t >> 6;
    const int wc0 = w * 128;
    const int l15 = lane & 15;
    const int kg = lane >> 4;

    float4v acc[8][2];
#pragma unroll
    for (int c = 0; c < 8; ++c)
#pragma unroll
        for (int rt = 0; rt < 2; ++rt) acc[c][rt] = (float4v)0.f;

    const ushort_t* ehp = eh + (size_t)(wc0 + l15) * D + 8 * kg;

#pragma unroll 4
    for (int d0 = 0; d0 < D; d0 += 32) {
        const short8v bh0 = *reinterpret_cast<const short8v*>(&zh[l15][d0 + 8 * kg]);
        const short8v bh1 = *reinterpret_cast<const short8v*>(&zh[16 + l15][d0 + 8 * kg]);
        const short8v bl0 = *reinterpret_cast<const short8v*>(&zl[l15][d0 + 8 * kg]);
        const short8v bl1 = *reinterpret_cast<const short8v*>(&zl[16 + l15][d0 + 8 * kg]);
#pragma unroll
        for (int c = 0; c < 8; ++c) {
            const short8v a = *reinterpret_cast<const short8v*>(ehp + c * 16 * D + d0);
            acc[c][0] = __builtin_amdgcn_mfma_f32_16x16x32_bf16(a, bh0, acc[c][0], 0, 0, 0);
            acc[c][1] = __builtin_amdgcn_mfma_f32_16x16x32_bf16(a, bh1, acc[c][1], 0, 0, 0);
            acc[c][0] = __builtin_amdgcn_mfma_f32_16x16x32_bf16(a, bl0, acc[c][0], 0, 0, 0);
            acc[c][1] = __builtin_amdgcn_mfma_f32_16x16x32_bf16(a, bl1, acc[c][1], 0, 0, 0);
        }
    }

    // ---- approx scores + per-row min
    float lmin0 = 3.0e38f, lmin1 = 3.0e38f;
#pragma unroll
    for (int c = 0; c < 8; ++c)
#pragma unroll
        for (int rt = 0; rt < 2; ++rt)
#pragma unroll
            for (int r = 0; r < 4; ++r) {
                const int code = wc0 + 16 * c + 4 * kg + r;
                const int row = rt * 16 + l15;
                float s = (lds_A[row] + lds_B[code]) - 2.0f * acc[c][rt][r];
                acc[c][rt][r] = s;
                if (rt == 0) lmin0 = fminf(lmin0, s);
                else lmin1 = fminf(lmin1, s);
            }
    lmin0 = fminf(lmin0, __shfl_xor(lmin0, 16));
    lmin0 = fminf(lmin0, __shfl_xor(lmin0, 32));
    lmin1 = fminf(lmin1, __shfl_xor(lmin1, 16));
    lmin1 = fminf(lmin1, __shfl_xor(lmin1, 32));
    if (lane < 16) {
        wmin[w][l15] = lmin0;
        wmin[w][16 + l15] = lmin1;
    }
    __syncthreads();
    if (t < 32) {
        rmin[t] = fminf(fminf(wmin[0][t], wmin[1][t]), fminf(wmin[2][t], wmin[3][t]));
        cnt[t] = 0;
    }
    __syncthreads();

    // ---- candidate collection (any possible exact winner is within EPS)
    int* cand = reinterpret_cast<int*>(&lds_scratch[0][0]);  // [32][15] used via cand[row*15+s]
#pragma unroll
    for (int c = 0; c < 8; ++c)
#pragma unroll
        for (int rt = 0; rt < 2; ++rt) {
            const int row = rt * 16 + l15;
            const float thr = rmin[row] + EPS_CAND;
#pragma unroll
            for (int r = 0; r < 4; ++r) {
                if (acc[c][rt][r] <= thr) {
                    const int code = wc0 + 16 * c + 4 * kg + r;
                    int slot = atomicAdd(&cnt[row], 1);
                    if (slot < 15) cand[row * 15 + slot] = code;
                }
            }
        }
    __syncthreads();

    // ---- exact pass: bitwise numpy-fp32 chain for rows with >=2 candidates.
    // zh buffer is dead now; alias reduction arrays onto it.
    float* ed = reinterpret_cast<float*>(&zh[0][0]);  // [8][32]
    int* ek = reinterpret_cast<int*>(ed + 256);       // [8][32]
    int* kb = ek + 256;                               // [32]
    {
        const int row = t & 31;
        const int ct = t >> 5;  // 0..7 candidate-threads per row
        int n = cnt[row];
        if (n > 15) n = 15;
        float bd = 3.0e38f;
        int bk = 0x7fffffff;
        if (n == 1) {
            if (ct == 0) {
                bd = -3.0e38f;
                bk = cand[row * 15];
            }
        } else {
            for (int s = ct; s < n; s += 8) {
                const int k = cand[row * 15 + s];
                const float* ep = cb + (size_t)k * D;
                float a = 0.f;
#pragma unroll 8
                for (int c = 0; c < D; ++c) a = fmaf(zf[c][row], ep[c], a);
                float dv;
                {
#pragma clang fp contract(off)
                    float t1 = lds_A[row] + lds_B[k];
                    dv = t1 - 2.0f * a;
                }
                if (dv < bd || (dv == bd && k < bk)) {
                    bd = dv;
                    bk = k;
                }
            }
        }
        ed[t] = bd;
        ek[t] = bk;
    }
    __syncthreads();
    if (t < 32) {
        float bd = ed[t];
        int bk = ek[t];
#pragma unroll
        for (int q = 1; q < 8; ++q) {
            float od = ed[q * 32 + t];
            int ok = ek[q * 32 + t];
            if (od < bd || (od == bd && ok < bk)) {
                bd = od;
                bk = ok;
            }
        }
        kb[t] = bk;
        out[IDX_OFF + row0 + t] = (float)bk;
    }
    __syncthreads();

    // ---- gather / straight-through write / loss partial (z from LDS)
    {
        const int j = t & 31;
        const int g = t >> 5;  // 0..7 -> c = g*32 + i
        const int kme = kb[j];
        const float* ep = cb + (size_t)kme * D;
        float* ob = out + (size_t)b * CHW + hw0;
        float accum = 0.f;
#pragma unroll 4
        for (int i = 0; i < 32; ++i) {
            const int c = g * 32 + i;
            float z = zf[c][j];
            float e = ep[c];
            ob[c * HW + j] = z + (e - z);
            float df = z - e;
            accum = fmaf(df, df, accum);
        }
#pragma unroll
        for (int m = 1; m < 64; m <<= 1) accum += __shfl_xor(accum, m);
        if ((t & 63) == 0) wpart[t >> 6] = accum;
    }
    __syncthreads();
    if (t == 0) part[blockIdx.x] = (wpart[0] + wpart[1]) + (wpart[2] + wpart[3]);
}

// ---------------------------------------------------------------------------
// Kernel 3: final loss reduction (2048 partials, fp64, deterministic).
__global__ void vq_finish(const float* __restrict__ part, float* __restrict__ out) {
    const int t = threadIdx.x;  // 256 threads
    double s = 0.0;
#pragma unroll
    for (int i = 0; i < 8; ++i) s += (double)part[t + 256 * i];
#pragma unroll
    for (int m = 1; m < 64; m <<= 1) s += __shfl_xor(s, m);
    __shared__ double wsum[4];
    if ((t & 63) == 0) wsum[t >> 6] = s;
    __syncthreads();
    if (t == 0) {
        double mean = (wsum[0] + wsum[1] + wsum[2] + wsum[3]) / (double)ZQ_SIZE;
        out[LOSS0_OFF] = (float)mean;
        out[LOSS1_OFF] = (float)mean;
    }
}

// ---------------------------------------------------------------------------
extern "C" void kernel_launch(void* const* d_in, const int* in_sizes, int n_in,
                              void* d_out, int out_size, void* d_ws, size_t ws_size,
                              hipStream_t stream) {
    const float* z_e = (const float*)d_in[0];
    const float* cb = (const float*)d_in[1];
    float* out = (float*)d_out;
    float* ws = (float*)d_ws;

    const ushort_t* eh = (const ushort_t*)ws;
    float* Bv = ws + WS_B;
    float* part = ws + WS_PART;

    vq_prep<<<K, D, 0, stream>>>(cb, ws);
    vq_mega<<<NBLK, 256, 0, stream>>>(z_e, cb, eh, Bv, part, out);
    vq_finish<<<1, 256, 0, stream>>>(part, out);
}